// Round 14
// baseline (596.073 us; speedup 1.0000x reference)
//
#include <hip/hip_runtime.h>
#include <hip/hip_bf16.h>
#include <math.h>

#define D 64
#define NEG 0.2f
#define WPB 4
#define BLK 256
#define DPB 128
#define MAXNB 1024
#define CHUNK 16384
#define PCHUNK 8192

typedef __attribute__((ext_vector_type(8))) short bf8;
typedef __attribute__((ext_vector_type(4))) float f4;
typedef __attribute__((ext_vector_type(4))) int i4;

__device__ __forceinline__ float lrelu(float v) { return v > 0.f ? v : NEG * v; }

__device__ __forceinline__ unsigned short f2bf(float f) {
    unsigned u = __float_as_uint(f);
    u = (u + 0x7fffu + ((u >> 16) & 1u)) >> 16;   // RTNE
    return (unsigned short)u;
}
// fast tanh: 1 - 2/(e^{2x}+1). v_rcp_f32 ~1ulp; saturates correctly at +-inf.
__device__ __forceinline__ float ftanh(float x) {
    float t = __expf(2.f * x);
    return fmaf(-2.f, __builtin_amdgcn_rcpf(t + 1.f), 1.f);
}
__device__ __forceinline__ bf8 ld_frag_g(const unsigned short* p) {
    i4 v = *(const i4*)p;
    return __builtin_bit_cast(bf8, v);
}

__device__ __forceinline__ const int* edge_ptr(const int* e0, const int* e1,
                                               const int* e2, const int* e3, int r)
{
    return (r == 0) ? e0 : (r == 1) ? e1 : (r == 2) ? e2 : e3;
}

// ---------------- bucketed CSR build ----------------

__global__ __launch_bounds__(256) void k_bcount(
    const int* __restrict__ e0, const int* __restrict__ e1,
    const int* __restrict__ e2, const int* __restrict__ e3,
    int* __restrict__ bcnt, int E, int NB)
{
    int r = blockIdx.y;
    const int* dst = edge_ptr(e0, e1, e2, e3, r) + E;
    __shared__ int hist[MAXNB];
    for (int i = threadIdx.x; i < NB; i += 256) hist[i] = 0;
    __syncthreads();
    int base = blockIdx.x * CHUNK;
    int end = base + CHUNK < E ? base + CHUNK : E;
    for (int i = base + threadIdx.x; i < end; i += 256)
        atomicAdd(&hist[dst[i] >> 7], 1);
    __syncthreads();
    for (int i = threadIdx.x; i < NB; i += 256)
        if (hist[i]) atomicAdd(&bcnt[r * NB + i], hist[i]);
}

__global__ __launch_bounds__(1024) void k_bscan(
    const int* __restrict__ bcnt, int* __restrict__ boff,
    int* __restrict__ bcur, int* __restrict__ prefix, int E, int N, int NB)
{
    int r = blockIdx.y;
    __shared__ int sh[1024];
    int t = threadIdx.x;
    int v = (t < NB) ? bcnt[r * NB + t] : 0;
    sh[t] = v;
    __syncthreads();
    for (int off = 1; off < 1024; off <<= 1) {
        int add = (t >= off) ? sh[t - off] : 0;
        __syncthreads();
        sh[t] += add;
        __syncthreads();
    }
    if (t < NB) {
        int excl = sh[t] - v;
        boff[r * (NB + 1) + t] = excl;
        bcur[r * NB + t] = excl;
    }
    if (t == 0) {
        boff[r * (NB + 1) + NB] = E;
        prefix[(size_t)r * (N + 1) + N] = E;
    }
}

// LDS counting-sort partition: bucket-sort the chunk in LDS, reserve each
// bucket's global run with ONE atomic, stream out in position order.
__global__ __launch_bounds__(256) void k_part(
    const int* __restrict__ e0, const int* __restrict__ e1,
    const int* __restrict__ e2, const int* __restrict__ e3,
    int* __restrict__ gcur, unsigned* __restrict__ staging, int E, int NB)
{
    __shared__ unsigned vals[PCHUNK];          // 32 KB
    __shared__ unsigned short bkt[PCHUNK];     // 16 KB
    __shared__ int hist[MAXNB];                // 4 KB
    __shared__ int sbase[MAXNB];               // 4 KB
    __shared__ int gdelta[MAXNB];              // 4 KB
    __shared__ int ssum[256];                  // 1 KB
    int r = blockIdx.y;
    const int* ep = edge_ptr(e0, e1, e2, e3, r);
    const int* srcp = ep;
    const int* dstp = ep + E;
    int t = threadIdx.x;
    for (int j = t; j < MAXNB; j += 256) hist[j] = 0;
    __syncthreads();
    int begin = blockIdx.x * PCHUNK;
    int end = begin + PCHUNK < E ? begin + PCHUNK : E;
    int cnt = end - begin;
    for (int i = begin + t; i < end; i += 256)
        atomicAdd(&hist[dstp[i] >> 7], 1);
    __syncthreads();
    int h0 = hist[t * 4], h1 = hist[t * 4 + 1], h2 = hist[t * 4 + 2], h3 = hist[t * 4 + 3];
    int lsum = h0 + h1 + h2 + h3;
    ssum[t] = lsum;
    __syncthreads();
    for (int off = 1; off < 256; off <<= 1) {
        int a = (t >= off) ? ssum[t - off] : 0;
        __syncthreads();
        ssum[t] += a;
        __syncthreads();
    }
    int ex = ssum[t] - lsum;
    sbase[t * 4] = ex;
    sbase[t * 4 + 1] = ex + h0;
    sbase[t * 4 + 2] = ex + h0 + h1;
    sbase[t * 4 + 3] = ex + h0 + h1 + h2;
    __syncthreads();
    for (int j = t; j < NB; j += 256) {
        int c = hist[j];
        int gb = c ? atomicAdd(&gcur[r * NB + j], c) : 0;
        gdelta[j] = gb - sbase[j];
    }
    __syncthreads();
    for (int j = t; j < MAXNB; j += 256) hist[j] = 0;   // reuse as rank counter
    __syncthreads();
    for (int i = begin + t; i < end; i += 256) {
        int d = dstp[i];
        int s = srcp[i];
        int b = d >> 7;
        int rank = atomicAdd(&hist[b], 1);
        int p = sbase[b] + rank;
        vals[p] = ((unsigned)s << 7) | (unsigned)(d & 127);
        bkt[p] = (unsigned short)b;
    }
    __syncthreads();
    unsigned* stg = staging + (size_t)r * E;
    for (int p = t; p < cnt; p += 256)
        stg[p + gdelta[bkt[p]]] = vals[p];
}

__global__ __launch_bounds__(256) void k_place(
    const unsigned* __restrict__ staging, const int* __restrict__ boff,
    int* __restrict__ prefix, int* __restrict__ srcs, int N, int E, int NB)
{
    int r = blockIdx.y;
    int b = blockIdx.x;
    int t = threadIdx.x;
    __shared__ int lcount[DPB];
    __shared__ int ls[DPB];
    __shared__ int lcur[DPB];
    int gbase = boff[r * (NB + 1) + b];
    int bcnt = boff[r * (NB + 1) + b + 1] - gbase;
    if (t < DPB) lcount[t] = 0;
    __syncthreads();
    const unsigned* st = staging + (size_t)r * E + gbase;
    for (int i = t; i < bcnt; i += 256)
        atomicAdd(&lcount[st[i] & 127], 1);
    __syncthreads();
    if (t < DPB) ls[t] = lcount[t];
    __syncthreads();
    for (int off = 1; off < DPB; off <<= 1) {
        int add = (t < DPB && t >= off) ? ls[t - off] : 0;
        __syncthreads();
        if (t < DPB) ls[t] += add;
        __syncthreads();
    }
    int lo = b * DPB;
    if (t < DPB) {
        int excl = ls[t] - lcount[t];
        lcur[t] = excl;
        int d = lo + t;
        if (d < N) prefix[(size_t)r * (N + 1) + d] = gbase + excl;
    }
    __syncthreads();
    for (int i = t; i < bcnt; i += 256) {
        unsigned v = st[i];
        int pos = atomicAdd(&lcur[v & 127], 1);
        srcs[(size_t)r * E + gbase + pos] = (int)(v >> 7);
    }
}

// ---------------- setup: weight packing ----------------

__global__ __launch_bounds__(64) void k_pack(
    const float* __restrict__ gatW, const float* __restrict__ atS,
    const float* __restrict__ atD, const float* __restrict__ W1,
    const float* __restrict__ W2, unsigned short* __restrict__ WgP,
    unsigned short* __restrict__ W1P, unsigned short* __restrict__ W2P)
{
    int f = blockIdx.x;
    int L = threadIdx.x;
    int kg = L >> 4, c = L & 15;
    unsigned short vals[8];
    unsigned short* dst;
    if (f < 80) {
        int m = f / 10, rem = f % 10;
        int l = m / 4, r = m % 4;
        int kc = rem / 5, ct = rem % 5;
        const float* W = gatW + (size_t)(l * 4 + r) * D * D;
        if (ct < 4) {
#pragma unroll
            for (int j = 0; j < 8; j++) {
                int k = kc * 32 + kg * 8 + j;
                vals[j] = f2bf(W[k * D + ct * 16 + c]);
            }
        } else {
            const float* att = (c == 0) ? atS + (size_t)(l * 4 + r) * D
                                        : atD + (size_t)(l * 4 + r) * D;
#pragma unroll
            for (int j = 0; j < 8; j++) {
                int k = kc * 32 + kg * 8 + j;
                float s = 0.f;
                if (c < 2)
                    for (int cc = 0; cc < D; cc++) s += W[k * D + cc] * att[cc];
                vals[j] = f2bf(s);
            }
        }
        dst = WgP + ((size_t)f * 64 + L) * 8;
    } else if (f < 160) {
        int f2 = f - 80;
        int l = f2 / 40, rem = f2 % 40;
        int kc = rem / 4, ct = rem % 4;
        const float* W = W1 + (size_t)l * 5 * D * D;
#pragma unroll
        for (int j = 0; j < 8; j++) {
            int k = kc * 32 + kg * 8 + j;
            vals[j] = f2bf(W[k * D + ct * 16 + c]);
        }
        dst = W1P + ((size_t)f2 * 64 + L) * 8;
    } else {
        int f3 = f - 160;
        int l = f3 / 8, rem = f3 % 8;
        int kc = rem / 4, ct = rem % 4;
        const float* W = W2 + (size_t)l * D * D;
#pragma unroll
        for (int j = 0; j < 8; j++) {
            int k = kc * 32 + kg * 8 + j;
            vals[j] = f2bf(W[k * D + ct * 16 + c]);
        }
        dst = W2P + ((size_t)f3 * 64 + L) * 8;
    }
    i4 v = __builtin_bit_cast(i4, *(bf8*)vals);
    *(i4*)dst = v;
}

// ---------------- MFMA compute ----------------

__device__ __forceinline__ void gemm_h_body(
    bf8 a0, bf8 a1, const unsigned short* __restrict__ WgPl,
    unsigned short* __restrict__ h, float* __restrict__ a_s,
    float* __restrict__ a_d, int n0, int kg, int lo, int L, int N)
{
#pragma unroll
    for (int r = 0; r < 4; r++) {
        const unsigned short* Wbase = WgPl + (size_t)r * 10 * 512;
#pragma unroll
        for (int ct = 0; ct < 5; ct++) {
            f4 acc = {0.f, 0.f, 0.f, 0.f};
            bf8 b0 = ld_frag_g(Wbase + (size_t)ct * 512 + (size_t)L * 8);
            bf8 b1 = ld_frag_g(Wbase + (size_t)(5 + ct) * 512 + (size_t)L * 8);
            acc = __builtin_amdgcn_mfma_f32_16x16x32_bf16(a0, b0, acc, 0, 0, 0);
            acc = __builtin_amdgcn_mfma_f32_16x16x32_bf16(a1, b1, acc, 0, 0, 0);
#pragma unroll
            for (int q = 0; q < 4; q++) {
                int node = n0 + kg * 4 + q;
                if (node < N) {
                    if (ct < 4)
                        h[((size_t)r * N + node) * D + ct * 16 + lo] = f2bf(acc[q]);
                    else if (lo == 0)
                        a_s[(size_t)r * N + node] = acc[q];
                    else if (lo == 1)
                        a_d[(size_t)r * N + node] = acc[q];
                }
            }
        }
    }
}

// fused: x fp32 -> bf16 cast (writes xb for k_mlp plane 0) + layer-0 gemm_h.
// Removes the standalone k_xcast dispatch and gemm_h's 12.8MB xb re-read.
__global__ __launch_bounds__(BLK) void k_gxh(
    const float* __restrict__ x, unsigned short* __restrict__ xb,
    const unsigned short* __restrict__ WgPl,
    unsigned short* __restrict__ h, float* __restrict__ a_s,
    float* __restrict__ a_d, int N)
{
    int w = threadIdx.x >> 6, L = threadIdx.x & 63;
    int n0 = blockIdx.x * 64 + w * 16;
    int lo = L & 15, kg = L >> 4;
    int nA = n0 + lo; if (nA >= N) nA = N - 1;

    const float* xr = x + (size_t)nA * D;
    float4 v0 = ((const float4*)(xr + kg * 8))[0];
    float4 v1 = ((const float4*)(xr + kg * 8))[1];
    float4 v2 = ((const float4*)(xr + 32 + kg * 8))[0];
    float4 v3 = ((const float4*)(xr + 32 + kg * 8))[1];
    unsigned short f0[8], f1[8];
    f0[0]=f2bf(v0.x); f0[1]=f2bf(v0.y); f0[2]=f2bf(v0.z); f0[3]=f2bf(v0.w);
    f0[4]=f2bf(v1.x); f0[5]=f2bf(v1.y); f0[6]=f2bf(v1.z); f0[7]=f2bf(v1.w);
    f1[0]=f2bf(v2.x); f1[1]=f2bf(v2.y); f1[2]=f2bf(v2.z); f1[3]=f2bf(v2.w);
    f1[4]=f2bf(v3.x); f1[5]=f2bf(v3.y); f1[6]=f2bf(v3.z); f1[7]=f2bf(v3.w);
    bf8 a0 = *(const bf8*)f0;
    bf8 a1 = *(const bf8*)f1;
    // side-effect: write xb (tail rows duplicated -> identical data, benign)
    unsigned short* xbr = xb + (size_t)nA * D;
    *(i4*)(xbr + kg * 8)      = __builtin_bit_cast(i4, a0);
    *(i4*)(xbr + 32 + kg * 8) = __builtin_bit_cast(i4, a1);

    gemm_h_body(a0, a1, WgPl, h, a_s, a_d, n0, kg, lo, L, N);
}

// GAT aggregation: 2 dsts per wave, dword (2-feature) lanes, deep unroll.
// (round-0 form, measured 118.9 us — rounds 10-12 refuted all inner-loop
// restructurings: perm hurts locality, dwordx2 halves MLP, deep unroll
// kills occupancy.)
__global__ __launch_bounds__(BLK) void k_agg(
    const unsigned short* __restrict__ h, const float* __restrict__ a_sall,
    const float* __restrict__ a_dall, const int* __restrict__ prefix,
    const int* __restrict__ srcsall, const float* __restrict__ gatB,
    unsigned short* __restrict__ g, int N, int E)
{
    __shared__ int2 pairs[WPB][64];
    int r = blockIdx.y;
    int w = threadIdx.x >> 6, lane = threadIdx.x & 63;
    int half = lane >> 5, fl = lane & 31;
    int d = (blockIdx.x * WPB + w) * 2 + half;
    if (d >= N) d = N - 1;

    const unsigned short* hr = h + (size_t)r * N * D;
    const float* a_src = a_sall + (size_t)r * N;
    const int* starts = prefix + (size_t)r * (N + 1);
    const int* srcs = srcsall + (size_t)r * E;

    int base = starts[d];
    int cnt = starts[d + 1] - base;
    float ad = a_dall[(size_t)r * N + d];

    float e_self = __expf(lrelu(a_src[d] + ad));
    float zpart = (fl == 0) ? e_self : 0.f;
    float accx, accy;
    {
        unsigned u = ((const unsigned*)(hr + (size_t)d * D))[fl];
        accx = e_self * __uint_as_float(u << 16);
        accy = e_self * __uint_as_float(u & 0xffff0000u);
    }

    int cntmax = max(cnt, __shfl_xor(cnt, 32));
    for (int c0 = 0; c0 < cntmax; c0 += 32) {
        int jj = c0 + fl;
        bool valid = jj < cnt;
        int s = valid ? srcs[base + jj] : 0;
        float e = valid ? __expf(lrelu(a_src[s] + ad)) : 0.f;
        zpart += e;
        pairs[w][lane] = make_int2(s * (int)(D * 2), __float_as_int(e));
        __threadfence_block();
        int lim = cntmax - c0; if (lim > 32) lim = 32;
        int rlim = (lim + 7) & ~7;               // pad entries have e=0
#pragma unroll 4
        for (int t = 0; t < rlim; t += 2) {
            i4 pv = *(const i4*)(&pairs[w][half * 32 + t]);
            unsigned uA = *(const unsigned*)((const char*)hr + pv.x + fl * 4);
            unsigned uB = *(const unsigned*)((const char*)hr + pv.z + fl * 4);
            float eA = __int_as_float(pv.y), eB = __int_as_float(pv.w);
            accx = fmaf(eA, __uint_as_float(uA << 16), accx);
            accy = fmaf(eA, __uint_as_float(uA & 0xffff0000u), accy);
            accx = fmaf(eB, __uint_as_float(uB << 16), accx);
            accy = fmaf(eB, __uint_as_float(uB & 0xffff0000u), accy);
        }
        __threadfence_block();
    }

    float z = zpart;
#pragma unroll
    for (int off = 16; off; off >>= 1) z += __shfl_xor(z, off);

    float rz = 1.f / z;
    float vlo = accx * rz + gatB[r * D + 2 * fl];
    float vhi = accy * rz + gatB[r * D + 2 * fl + 1];
    unsigned o = (unsigned)f2bf(vlo) | ((unsigned)f2bf(vhi) << 16);
    ((unsigned*)g)[((size_t)r * N + d) * 32 + fl] = o;
}

// fused MLP (+ next-layer gemm_h when !last)
__global__ __launch_bounds__(BLK) void k_mlp(
    const unsigned short* __restrict__ xb, const unsigned short* __restrict__ g,
    const unsigned short* __restrict__ W1Pl, const float* __restrict__ b1l,
    const unsigned short* __restrict__ W2Pl, const float* __restrict__ b2l,
    void* __restrict__ outp, int N, int last,
    const unsigned short* __restrict__ WgPn, unsigned short* __restrict__ hn,
    float* __restrict__ a_sn, float* __restrict__ a_dn)
{
    __shared__ unsigned short sh[WPB][16 * 80];
    int w = threadIdx.x >> 6, L = threadIdx.x & 63;
    int n0 = blockIdx.x * 64 + w * 16;
    int lo = L & 15, kg = L >> 4;
    int nA = n0 + lo; if (nA >= N) nA = N - 1;

    f4 acc[4];
#pragma unroll
    for (int ct = 0; ct < 4; ct++) acc[ct] = (f4){0.f, 0.f, 0.f, 0.f};

#pragma unroll
    for (int p = 0; p < 5; p++) {
        const unsigned short* plane = (p == 0) ? xb : g + (size_t)(p - 1) * N * D;
#pragma unroll
        for (int kc2 = 0; kc2 < 2; kc2++) {
            bf8 a = ld_frag_g(plane + (size_t)nA * D + kc2 * 32 + kg * 8);
            int kc = p * 2 + kc2;
#pragma unroll
            for (int ct = 0; ct < 4; ct++) {
                bf8 b = ld_frag_g(W1Pl + ((size_t)(kc * 4 + ct) * 512 + (size_t)L * 8));
                acc[ct] = __builtin_amdgcn_mfma_f32_16x16x32_bf16(a, b, acc[ct], 0, 0, 0);
            }
        }
    }

    unsigned short* tile = &sh[w][0];
#pragma unroll
    for (int ct = 0; ct < 4; ct++) {
        float bb = b1l[ct * 16 + lo];
#pragma unroll
        for (int q = 0; q < 4; q++)
            tile[(kg * 4 + q) * 80 + ct * 16 + lo] = f2bf(ftanh(acc[ct][q] + bb));
    }
    __syncthreads();

    f4 o[4];
#pragma unroll
    for (int ct = 0; ct < 4; ct++) o[ct] = (f4){0.f, 0.f, 0.f, 0.f};
#pragma unroll
    for (int kc = 0; kc < 2; kc++) {
        const unsigned short* ap = tile + lo * 80 + kc * 32 + kg * 8;
        i4 av = *(const i4*)ap;
        bf8 a = __builtin_bit_cast(bf8, av);
#pragma unroll
        for (int ct = 0; ct < 4; ct++) {
            bf8 b = ld_frag_g(W2Pl + ((size_t)(kc * 4 + ct) * 512 + (size_t)L * 8));
            o[ct] = __builtin_amdgcn_mfma_f32_16x16x32_bf16(a, b, o[ct], 0, 0, 0);
        }
    }
    __syncthreads();
#pragma unroll
    for (int ct = 0; ct < 4; ct++) {
        float bb = b2l[ct * 16 + lo];
#pragma unroll
        for (int q = 0; q < 4; q++) {
            int node = n0 + kg * 4 + q;
            int col = ct * 16 + lo;
            float v = o[ct][q] + bb;
            if (node < N) {
                if (last) ((float*)outp)[(size_t)node * D + col] = v;
                else ((unsigned short*)outp)[(size_t)node * D + col] = f2bf(v);
            }
            if (!last) tile[(kg * 4 + q) * 80 + col] = f2bf(v);
        }
    }
    if (last) return;

    __syncthreads();
    bf8 a0, a1;
    {
        i4 v0 = *(const i4*)(tile + lo * 80 + kg * 8);
        i4 v1 = *(const i4*)(tile + lo * 80 + 32 + kg * 8);
        a0 = __builtin_bit_cast(bf8, v0);
        a1 = __builtin_bit_cast(bf8, v1);
    }
    gemm_h_body(a0, a1, WgPn, hn, a_sn, a_dn, n0, kg, lo, L, N);
}

// ---------------- launch ----------------

extern "C" void kernel_launch(void* const* d_in, const int* in_sizes, int n_in,
                              void* d_out, int out_size, void* d_ws, size_t ws_size,
                              hipStream_t stream)
{
    const float* x    = (const float*)d_in[0];
    const int*   e0   = (const int*)d_in[1];
    const int*   e1   = (const int*)d_in[2];
    const int*   e2   = (const int*)d_in[3];
    const int*   e3   = (const int*)d_in[4];
    const float* gatW = (const float*)d_in[5];
    const float* atS  = (const float*)d_in[6];
    const float* atD  = (const float*)d_in[7];
    const float* gatB = (const float*)d_in[8];
    const float* W1   = (const float*)d_in[9];
    const float* b1   = (const float*)d_in[10];
    const float* W2   = (const float*)d_in[11];
    const float* b2   = (const float*)d_in[12];
    float* out = (float*)d_out;

    const int N = in_sizes[0] / D;
    const int E = in_sizes[1] / 2;
    const int NB = (N + DPB - 1) / DPB;

    size_t off = 0;
    auto alloc = [&](size_t bytes) { size_t o = off; off = (off + bytes + 255) & ~(size_t)255; return o; };
    unsigned short* xb    = (unsigned short*)((char*)d_ws + alloc((size_t)N * D * 2));
    unsigned short* xnext = (unsigned short*)((char*)d_ws + alloc((size_t)N * D * 2));
    unsigned short* h     = (unsigned short*)((char*)d_ws + alloc((size_t)4 * N * D * 2));
    unsigned short* g     = (unsigned short*)((char*)d_ws + alloc((size_t)4 * N * D * 2));
    unsigned* staging = (unsigned*)g;        // alias: CSR build precedes g use
    float* a_s   = (float*)((char*)d_ws + alloc((size_t)4 * N * 4));
    float* a_d   = (float*)((char*)d_ws + alloc((size_t)4 * N * 4));
    int* prefix  = (int*)((char*)d_ws + alloc((size_t)4 * (N + 1) * 4));
    int* srcs    = (int*)((char*)d_ws + alloc((size_t)4 * E * 4));
    int* bcnt    = (int*)((char*)d_ws + alloc((size_t)4 * NB * 4));
    int* boff    = (int*)((char*)d_ws + alloc((size_t)4 * (NB + 1) * 4));
    int* bcur    = (int*)((char*)d_ws + alloc((size_t)4 * NB * 4));
    unsigned short* WgP = (unsigned short*)((char*)d_ws + alloc((size_t)80 * 512 * 2));
    unsigned short* W1P = (unsigned short*)((char*)d_ws + alloc((size_t)80 * 512 * 2));
    unsigned short* W2P = (unsigned short*)((char*)d_ws + alloc((size_t)16 * 512 * 2));
    (void)ws_size;

    const int cntBlocks  = (E + CHUNK - 1) / CHUNK;
    const int partBlocks = (E + PCHUNK - 1) / PCHUNK;
    const int tileBlocks = (N + 63) / 64;
    const int aggBlocks  = (N + 7) / 8;   // 2 dsts/wave * 4 waves

    k_pack<<<176, 64, 0, stream>>>(gatW, atS, atD, W1, W2, WgP, W1P, W2P);

    hipMemsetAsync(bcnt, 0, (size_t)4 * NB * 4, stream);
    k_bcount<<<dim3(cntBlocks, 4), 256, 0, stream>>>(e0, e1, e2, e3, bcnt, E, NB);
    k_bscan<<<dim3(1, 4), 1024, 0, stream>>>(bcnt, boff, bcur, prefix, E, N, NB);
    k_part<<<dim3(partBlocks, 4), 256, 0, stream>>>(e0, e1, e2, e3, bcur, staging, E, NB);
    k_place<<<dim3(NB, 4), 256, 0, stream>>>(staging, boff, prefix, srcs, N, E, NB);

    // layer 0 (fused cast + gemm_h)
    k_gxh<<<tileBlocks, BLK, 0, stream>>>(x, xb, WgP, h, a_s, a_d, N);
    k_agg<<<dim3(aggBlocks, 4), BLK, 0, stream>>>(
        h, a_s, a_d, prefix, srcs, gatB, g, N, E);
    k_mlp<<<tileBlocks, BLK, 0, stream>>>(
        xb, g, W1P, b1, W2P, b2, xnext, N, 0,
        WgP + (size_t)40 * 512, h, a_s, a_d);   // fused layer-1 gemm_h

    // layer 1
    k_agg<<<dim3(aggBlocks, 4), BLK, 0, stream>>>(
        h, a_s, a_d, prefix, srcs, gatB + (size_t)4 * D, g, N, E);
    k_mlp<<<tileBlocks, BLK, 0, stream>>>(
        xnext, g, W1P + (size_t)40 * 512, b1 + D, W2P + (size_t)8 * 512, b2 + D,
        out, N, 1, nullptr, nullptr, nullptr, nullptr);
}

// Round 15
// 590.225 us; speedup vs baseline: 1.0099x; 1.0099x over previous
//
#include <hip/hip_runtime.h>
#include <hip/hip_bf16.h>
#include <math.h>

#define D 64
#define NEG 0.2f
#define WPB 4
#define BLK 256
#define DPB 128
#define MAXNB 1024
#define CHUNK 16384
#define PCHUNK 8192

typedef __attribute__((ext_vector_type(8))) short bf8;
typedef __attribute__((ext_vector_type(4))) float f4;
typedef __attribute__((ext_vector_type(4))) int i4;

__device__ __forceinline__ float lrelu(float v) { return v > 0.f ? v : NEG * v; }

__device__ __forceinline__ unsigned short f2bf(float f) {
    unsigned u = __float_as_uint(f);
    u = (u + 0x7fffu + ((u >> 16) & 1u)) >> 16;   // RTNE
    return (unsigned short)u;
}
// fast tanh: 1 - 2/(e^{2x}+1). v_rcp_f32 ~1ulp; saturates correctly at +-inf.
// Error ~1e-7 << bf16 quantum; output is bf16-rounded downstream.
__device__ __forceinline__ float ftanh(float x) {
    float t = __expf(2.f * x);
    return fmaf(-2.f, __builtin_amdgcn_rcpf(t + 1.f), 1.f);
}
__device__ __forceinline__ bf8 ld_frag_g(const unsigned short* p) {
    i4 v = *(const i4*)p;
    return __builtin_bit_cast(bf8, v);
}

__device__ __forceinline__ const int* edge_ptr(const int* e0, const int* e1,
                                               const int* e2, const int* e3, int r)
{
    return (r == 0) ? e0 : (r == 1) ? e1 : (r == 2) ? e2 : e3;
}

// ---------------- bucketed CSR build ----------------

__global__ __launch_bounds__(256) void k_bcount(
    const int* __restrict__ e0, const int* __restrict__ e1,
    const int* __restrict__ e2, const int* __restrict__ e3,
    int* __restrict__ bcnt, int E, int NB)
{
    int r = blockIdx.y;
    const int* dst = edge_ptr(e0, e1, e2, e3, r) + E;
    __shared__ int hist[MAXNB];
    for (int i = threadIdx.x; i < NB; i += 256) hist[i] = 0;
    __syncthreads();
    int base = blockIdx.x * CHUNK;
    int end = base + CHUNK < E ? base + CHUNK : E;
    for (int i = base + threadIdx.x; i < end; i += 256)
        atomicAdd(&hist[dst[i] >> 7], 1);
    __syncthreads();
    for (int i = threadIdx.x; i < NB; i += 256)
        if (hist[i]) atomicAdd(&bcnt[r * NB + i], hist[i]);
}

__global__ __launch_bounds__(1024) void k_bscan(
    const int* __restrict__ bcnt, int* __restrict__ boff,
    int* __restrict__ bcur, int* __restrict__ prefix, int E, int N, int NB)
{
    int r = blockIdx.y;
    __shared__ int sh[1024];
    int t = threadIdx.x;
    int v = (t < NB) ? bcnt[r * NB + t] : 0;
    sh[t] = v;
    __syncthreads();
    for (int off = 1; off < 1024; off <<= 1) {
        int add = (t >= off) ? sh[t - off] : 0;
        __syncthreads();
        sh[t] += add;
        __syncthreads();
    }
    if (t < NB) {
        int excl = sh[t] - v;
        boff[r * (NB + 1) + t] = excl;
        bcur[r * NB + t] = excl;
    }
    if (t == 0) {
        boff[r * (NB + 1) + NB] = E;
        prefix[(size_t)r * (N + 1) + N] = E;
    }
}

// LDS counting-sort partition: bucket-sort the chunk in LDS, reserve each
// bucket's global run with ONE atomic, stream out in position order.
__global__ __launch_bounds__(256) void k_part(
    const int* __restrict__ e0, const int* __restrict__ e1,
    const int* __restrict__ e2, const int* __restrict__ e3,
    int* __restrict__ gcur, unsigned* __restrict__ staging, int E, int NB)
{
    __shared__ unsigned vals[PCHUNK];          // 32 KB
    __shared__ unsigned short bkt[PCHUNK];     // 16 KB
    __shared__ int hist[MAXNB];                // 4 KB
    __shared__ int sbase[MAXNB];               // 4 KB
    __shared__ int gdelta[MAXNB];              // 4 KB
    __shared__ int ssum[256];                  // 1 KB
    int r = blockIdx.y;
    const int* ep = edge_ptr(e0, e1, e2, e3, r);
    const int* srcp = ep;
    const int* dstp = ep + E;
    int t = threadIdx.x;
    for (int j = t; j < MAXNB; j += 256) hist[j] = 0;
    __syncthreads();
    int begin = blockIdx.x * PCHUNK;
    int end = begin + PCHUNK < E ? begin + PCHUNK : E;
    int cnt = end - begin;
    for (int i = begin + t; i < end; i += 256)
        atomicAdd(&hist[dstp[i] >> 7], 1);
    __syncthreads();
    int h0 = hist[t * 4], h1 = hist[t * 4 + 1], h2 = hist[t * 4 + 2], h3 = hist[t * 4 + 3];
    int lsum = h0 + h1 + h2 + h3;
    ssum[t] = lsum;
    __syncthreads();
    for (int off = 1; off < 256; off <<= 1) {
        int a = (t >= off) ? ssum[t - off] : 0;
        __syncthreads();
        ssum[t] += a;
        __syncthreads();
    }
    int ex = ssum[t] - lsum;
    sbase[t * 4] = ex;
    sbase[t * 4 + 1] = ex + h0;
    sbase[t * 4 + 2] = ex + h0 + h1;
    sbase[t * 4 + 3] = ex + h0 + h1 + h2;
    __syncthreads();
    for (int j = t; j < NB; j += 256) {
        int c = hist[j];
        int gb = c ? atomicAdd(&gcur[r * NB + j], c) : 0;
        gdelta[j] = gb - sbase[j];
    }
    __syncthreads();
    for (int j = t; j < MAXNB; j += 256) hist[j] = 0;   // reuse as rank counter
    __syncthreads();
    for (int i = begin + t; i < end; i += 256) {
        int d = dstp[i];
        int s = srcp[i];
        int b = d >> 7;
        int rank = atomicAdd(&hist[b], 1);
        int p = sbase[b] + rank;
        vals[p] = ((unsigned)s << 7) | (unsigned)(d & 127);
        bkt[p] = (unsigned short)b;
    }
    __syncthreads();
    unsigned* stg = staging + (size_t)r * E;
    for (int p = t; p < cnt; p += 256)
        stg[p + gdelta[bkt[p]]] = vals[p];
}

__global__ __launch_bounds__(256) void k_place(
    const unsigned* __restrict__ staging, const int* __restrict__ boff,
    int* __restrict__ prefix, int* __restrict__ srcs, int N, int E, int NB)
{
    int r = blockIdx.y;
    int b = blockIdx.x;
    int t = threadIdx.x;
    __shared__ int lcount[DPB];
    __shared__ int ls[DPB];
    __shared__ int lcur[DPB];
    int gbase = boff[r * (NB + 1) + b];
    int bcnt = boff[r * (NB + 1) + b + 1] - gbase;
    if (t < DPB) lcount[t] = 0;
    __syncthreads();
    const unsigned* st = staging + (size_t)r * E + gbase;
    for (int i = t; i < bcnt; i += 256)
        atomicAdd(&lcount[st[i] & 127], 1);
    __syncthreads();
    if (t < DPB) ls[t] = lcount[t];
    __syncthreads();
    for (int off = 1; off < DPB; off <<= 1) {
        int add = (t < DPB && t >= off) ? ls[t - off] : 0;
        __syncthreads();
        if (t < DPB) ls[t] += add;
        __syncthreads();
    }
    int lo = b * DPB;
    if (t < DPB) {
        int excl = ls[t] - lcount[t];
        lcur[t] = excl;
        int d = lo + t;
        if (d < N) prefix[(size_t)r * (N + 1) + d] = gbase + excl;
    }
    __syncthreads();
    for (int i = t; i < bcnt; i += 256) {
        unsigned v = st[i];
        int pos = atomicAdd(&lcur[v & 127], 1);
        srcs[(size_t)r * E + gbase + pos] = (int)(v >> 7);
    }
}

// ---------------- setup: cast + weight packing ----------------

__global__ __launch_bounds__(256) void k_xcast(
    const float* __restrict__ x, unsigned short* __restrict__ xb, int n4)
{
    int i = blockIdx.x * 256 + threadIdx.x;
    if (i < n4) {
        float4 v = ((const float4*)x)[i];
        ushort4 o;
        o.x = f2bf(v.x); o.y = f2bf(v.y); o.z = f2bf(v.z); o.w = f2bf(v.w);
        ((ushort4*)xb)[i] = o;
    }
}

__global__ __launch_bounds__(64) void k_pack(
    const float* __restrict__ gatW, const float* __restrict__ atS,
    const float* __restrict__ atD, const float* __restrict__ W1,
    const float* __restrict__ W2, unsigned short* __restrict__ WgP,
    unsigned short* __restrict__ W1P, unsigned short* __restrict__ W2P)
{
    int f = blockIdx.x;
    int L = threadIdx.x;
    int kg = L >> 4, c = L & 15;
    unsigned short vals[8];
    unsigned short* dst;
    if (f < 80) {
        int m = f / 10, rem = f % 10;
        int l = m / 4, r = m % 4;
        int kc = rem / 5, ct = rem % 5;
        const float* W = gatW + (size_t)(l * 4 + r) * D * D;
        if (ct < 4) {
#pragma unroll
            for (int j = 0; j < 8; j++) {
                int k = kc * 32 + kg * 8 + j;
                vals[j] = f2bf(W[k * D + ct * 16 + c]);
            }
        } else {
            const float* att = (c == 0) ? atS + (size_t)(l * 4 + r) * D
                                        : atD + (size_t)(l * 4 + r) * D;
#pragma unroll
            for (int j = 0; j < 8; j++) {
                int k = kc * 32 + kg * 8 + j;
                float s = 0.f;
                if (c < 2)
                    for (int cc = 0; cc < D; cc++) s += W[k * D + cc] * att[cc];
                vals[j] = f2bf(s);
            }
        }
        dst = WgP + ((size_t)f * 64 + L) * 8;
    } else if (f < 160) {
        int f2 = f - 80;
        int l = f2 / 40, rem = f2 % 40;
        int kc = rem / 4, ct = rem % 4;
        const float* W = W1 + (size_t)l * 5 * D * D;
#pragma unroll
        for (int j = 0; j < 8; j++) {
            int k = kc * 32 + kg * 8 + j;
            vals[j] = f2bf(W[k * D + ct * 16 + c]);
        }
        dst = W1P + ((size_t)f2 * 64 + L) * 8;
    } else {
        int f3 = f - 160;
        int l = f3 / 8, rem = f3 % 8;
        int kc = rem / 4, ct = rem % 4;
        const float* W = W2 + (size_t)l * D * D;
#pragma unroll
        for (int j = 0; j < 8; j++) {
            int k = kc * 32 + kg * 8 + j;
            vals[j] = f2bf(W[k * D + ct * 16 + c]);
        }
        dst = W2P + ((size_t)f3 * 64 + L) * 8;
    }
    i4 v = __builtin_bit_cast(i4, *(bf8*)vals);
    *(i4*)dst = v;
}

// ---------------- MFMA compute ----------------

__device__ __forceinline__ void gemm_h_body(
    bf8 a0, bf8 a1, const unsigned short* __restrict__ WgPl,
    unsigned short* __restrict__ h, float* __restrict__ a_s,
    float* __restrict__ a_d, int n0, int kg, int lo, int L, int N)
{
#pragma unroll
    for (int r = 0; r < 4; r++) {
        const unsigned short* Wbase = WgPl + (size_t)r * 10 * 512;
#pragma unroll
        for (int ct = 0; ct < 5; ct++) {
            f4 acc = {0.f, 0.f, 0.f, 0.f};
            bf8 b0 = ld_frag_g(Wbase + (size_t)ct * 512 + (size_t)L * 8);
            bf8 b1 = ld_frag_g(Wbase + (size_t)(5 + ct) * 512 + (size_t)L * 8);
            acc = __builtin_amdgcn_mfma_f32_16x16x32_bf16(a0, b0, acc, 0, 0, 0);
            acc = __builtin_amdgcn_mfma_f32_16x16x32_bf16(a1, b1, acc, 0, 0, 0);
#pragma unroll
            for (int q = 0; q < 4; q++) {
                int node = n0 + kg * 4 + q;
                if (node < N) {
                    if (ct < 4)
                        h[((size_t)r * N + node) * D + ct * 16 + lo] = f2bf(acc[q]);
                    else if (lo == 0)
                        a_s[(size_t)r * N + node] = acc[q];
                    else if (lo == 1)
                        a_d[(size_t)r * N + node] = acc[q];
                }
            }
        }
    }
}

__global__ __launch_bounds__(BLK) void k_gemm_h(
    const unsigned short* __restrict__ xb, const unsigned short* __restrict__ WgPl,
    unsigned short* __restrict__ h, float* __restrict__ a_s,
    float* __restrict__ a_d, int N)
{
    int w = threadIdx.x >> 6, L = threadIdx.x & 63;
    int n0 = blockIdx.x * 64 + w * 16;
    int lo = L & 15, kg = L >> 4;
    int nA = n0 + lo; if (nA >= N) nA = N - 1;
    bf8 a0 = ld_frag_g(xb + (size_t)nA * D + kg * 8);
    bf8 a1 = ld_frag_g(xb + (size_t)nA * D + 32 + kg * 8);
    gemm_h_body(a0, a1, WgPl, h, a_s, a_d, n0, kg, lo, L, N);
}

// GAT aggregation: 2 dsts per wave, dword (2-feature) lanes, deep unroll.
// (round-0 form, measured 118.9 us — rounds 10-12 refuted all inner-loop
// restructurings: perm hurts locality, dwordx2 halves MLP, deep unroll
// kills occupancy. Round 14 refuted cast+gemm_h fusion.)
__global__ __launch_bounds__(BLK) void k_agg(
    const unsigned short* __restrict__ h, const float* __restrict__ a_sall,
    const float* __restrict__ a_dall, const int* __restrict__ prefix,
    const int* __restrict__ srcsall, const float* __restrict__ gatB,
    unsigned short* __restrict__ g, int N, int E)
{
    __shared__ int2 pairs[WPB][64];
    int r = blockIdx.y;
    int w = threadIdx.x >> 6, lane = threadIdx.x & 63;
    int half = lane >> 5, fl = lane & 31;
    int d = (blockIdx.x * WPB + w) * 2 + half;
    if (d >= N) d = N - 1;

    const unsigned short* hr = h + (size_t)r * N * D;
    const float* a_src = a_sall + (size_t)r * N;
    const int* starts = prefix + (size_t)r * (N + 1);
    const int* srcs = srcsall + (size_t)r * E;

    int base = starts[d];
    int cnt = starts[d + 1] - base;
    float ad = a_dall[(size_t)r * N + d];

    float e_self = __expf(lrelu(a_src[d] + ad));
    float zpart = (fl == 0) ? e_self : 0.f;
    float accx, accy;
    {
        unsigned u = ((const unsigned*)(hr + (size_t)d * D))[fl];
        accx = e_self * __uint_as_float(u << 16);
        accy = e_self * __uint_as_float(u & 0xffff0000u);
    }

    int cntmax = max(cnt, __shfl_xor(cnt, 32));
    for (int c0 = 0; c0 < cntmax; c0 += 32) {
        int jj = c0 + fl;
        bool valid = jj < cnt;
        int s = valid ? srcs[base + jj] : 0;
        float e = valid ? __expf(lrelu(a_src[s] + ad)) : 0.f;
        zpart += e;
        pairs[w][lane] = make_int2(s * (int)(D * 2), __float_as_int(e));
        __threadfence_block();
        int lim = cntmax - c0; if (lim > 32) lim = 32;
        int rlim = (lim + 7) & ~7;               // pad entries have e=0
#pragma unroll 4
        for (int t = 0; t < rlim; t += 2) {
            i4 pv = *(const i4*)(&pairs[w][half * 32 + t]);
            unsigned uA = *(const unsigned*)((const char*)hr + pv.x + fl * 4);
            unsigned uB = *(const unsigned*)((const char*)hr + pv.z + fl * 4);
            float eA = __int_as_float(pv.y), eB = __int_as_float(pv.w);
            accx = fmaf(eA, __uint_as_float(uA << 16), accx);
            accy = fmaf(eA, __uint_as_float(uA & 0xffff0000u), accy);
            accx = fmaf(eB, __uint_as_float(uB << 16), accx);
            accy = fmaf(eB, __uint_as_float(uB & 0xffff0000u), accy);
        }
        __threadfence_block();
    }

    float z = zpart;
#pragma unroll
    for (int off = 16; off; off >>= 1) z += __shfl_xor(z, off);

    float rz = 1.f / z;
    float vlo = accx * rz + gatB[r * D + 2 * fl];
    float vhi = accy * rz + gatB[r * D + 2 * fl + 1];
    unsigned o = (unsigned)f2bf(vlo) | ((unsigned)f2bf(vhi) << 16);
    ((unsigned*)g)[((size_t)r * N + d) * 32 + fl] = o;
}

// fused MLP (+ next-layer gemm_h when !last)
__global__ __launch_bounds__(BLK) void k_mlp(
    const unsigned short* __restrict__ xb, const unsigned short* __restrict__ g,
    const unsigned short* __restrict__ W1Pl, const float* __restrict__ b1l,
    const unsigned short* __restrict__ W2Pl, const float* __restrict__ b2l,
    void* __restrict__ outp, int N, int last,
    const unsigned short* __restrict__ WgPn, unsigned short* __restrict__ hn,
    float* __restrict__ a_sn, float* __restrict__ a_dn)
{
    __shared__ unsigned short sh[WPB][16 * 80];
    int w = threadIdx.x >> 6, L = threadIdx.x & 63;
    int n0 = blockIdx.x * 64 + w * 16;
    int lo = L & 15, kg = L >> 4;
    int nA = n0 + lo; if (nA >= N) nA = N - 1;

    f4 acc[4];
#pragma unroll
    for (int ct = 0; ct < 4; ct++) acc[ct] = (f4){0.f, 0.f, 0.f, 0.f};

#pragma unroll
    for (int p = 0; p < 5; p++) {
        const unsigned short* plane = (p == 0) ? xb : g + (size_t)(p - 1) * N * D;
#pragma unroll
        for (int kc2 = 0; kc2 < 2; kc2++) {
            bf8 a = ld_frag_g(plane + (size_t)nA * D + kc2 * 32 + kg * 8);
            int kc = p * 2 + kc2;
#pragma unroll
            for (int ct = 0; ct < 4; ct++) {
                bf8 b = ld_frag_g(W1Pl + ((size_t)(kc * 4 + ct) * 512 + (size_t)L * 8));
                acc[ct] = __builtin_amdgcn_mfma_f32_16x16x32_bf16(a, b, acc[ct], 0, 0, 0);
            }
        }
    }

    unsigned short* tile = &sh[w][0];
#pragma unroll
    for (int ct = 0; ct < 4; ct++) {
        float bb = b1l[ct * 16 + lo];
#pragma unroll
        for (int q = 0; q < 4; q++)
            tile[(kg * 4 + q) * 80 + ct * 16 + lo] = f2bf(ftanh(acc[ct][q] + bb));
    }
    __syncthreads();

    f4 o[4];
#pragma unroll
    for (int ct = 0; ct < 4; ct++) o[ct] = (f4){0.f, 0.f, 0.f, 0.f};
#pragma unroll
    for (int kc = 0; kc < 2; kc++) {
        const unsigned short* ap = tile + lo * 80 + kc * 32 + kg * 8;
        i4 av = *(const i4*)ap;
        bf8 a = __builtin_bit_cast(bf8, av);
#pragma unroll
        for (int ct = 0; ct < 4; ct++) {
            bf8 b = ld_frag_g(W2Pl + ((size_t)(kc * 4 + ct) * 512 + (size_t)L * 8));
            o[ct] = __builtin_amdgcn_mfma_f32_16x16x32_bf16(a, b, o[ct], 0, 0, 0);
        }
    }
    __syncthreads();
#pragma unroll
    for (int ct = 0; ct < 4; ct++) {
        float bb = b2l[ct * 16 + lo];
#pragma unroll
        for (int q = 0; q < 4; q++) {
            int node = n0 + kg * 4 + q;
            int col = ct * 16 + lo;
            float v = o[ct][q] + bb;
            if (node < N) {
                if (last) ((float*)outp)[(size_t)node * D + col] = v;
                else ((unsigned short*)outp)[(size_t)node * D + col] = f2bf(v);
            }
            if (!last) tile[(kg * 4 + q) * 80 + col] = f2bf(v);
        }
    }
    if (last) return;

    __syncthreads();
    bf8 a0, a1;
    {
        i4 v0 = *(const i4*)(tile + lo * 80 + kg * 8);
        i4 v1 = *(const i4*)(tile + lo * 80 + 32 + kg * 8);
        a0 = __builtin_bit_cast(bf8, v0);
        a1 = __builtin_bit_cast(bf8, v1);
    }
    gemm_h_body(a0, a1, WgPn, hn, a_sn, a_dn, n0, kg, lo, L, N);
}

// ---------------- launch ----------------

extern "C" void kernel_launch(void* const* d_in, const int* in_sizes, int n_in,
                              void* d_out, int out_size, void* d_ws, size_t ws_size,
                              hipStream_t stream)
{
    const float* x    = (const float*)d_in[0];
    const int*   e0   = (const int*)d_in[1];
    const int*   e1   = (const int*)d_in[2];
    const int*   e2   = (const int*)d_in[3];
    const int*   e3   = (const int*)d_in[4];
    const float* gatW = (const float*)d_in[5];
    const float* atS  = (const float*)d_in[6];
    const float* atD  = (const float*)d_in[7];
    const float* gatB = (const float*)d_in[8];
    const float* W1   = (const float*)d_in[9];
    const float* b1   = (const float*)d_in[10];
    const float* W2   = (const float*)d_in[11];
    const float* b2   = (const float*)d_in[12];
    float* out = (float*)d_out;

    const int N = in_sizes[0] / D;
    const int E = in_sizes[1] / 2;
    const int NB = (N + DPB - 1) / DPB;

    size_t off = 0;
    auto alloc = [&](size_t bytes) { size_t o = off; off = (off + bytes + 255) & ~(size_t)255; return o; };
    unsigned short* xb    = (unsigned short*)((char*)d_ws + alloc((size_t)N * D * 2));
    unsigned short* xnext = (unsigned short*)((char*)d_ws + alloc((size_t)N * D * 2));
    unsigned short* h     = (unsigned short*)((char*)d_ws + alloc((size_t)4 * N * D * 2));
    unsigned short* g     = (unsigned short*)((char*)d_ws + alloc((size_t)4 * N * D * 2));
    unsigned* staging = (unsigned*)g;        // alias: CSR build precedes g use
    float* a_s   = (float*)((char*)d_ws + alloc((size_t)4 * N * 4));
    float* a_d   = (float*)((char*)d_ws + alloc((size_t)4 * N * 4));
    int* prefix  = (int*)((char*)d_ws + alloc((size_t)4 * (N + 1) * 4));
    int* srcs    = (int*)((char*)d_ws + alloc((size_t)4 * E * 4));
    int* bcnt    = (int*)((char*)d_ws + alloc((size_t)4 * NB * 4));
    int* boff    = (int*)((char*)d_ws + alloc((size_t)4 * (NB + 1) * 4));
    int* bcur    = (int*)((char*)d_ws + alloc((size_t)4 * NB * 4));
    unsigned short* WgP = (unsigned short*)((char*)d_ws + alloc((size_t)80 * 512 * 2));
    unsigned short* W1P = (unsigned short*)((char*)d_ws + alloc((size_t)80 * 512 * 2));
    unsigned short* W2P = (unsigned short*)((char*)d_ws + alloc((size_t)16 * 512 * 2));
    (void)ws_size;

    const int cntBlocks  = (E + CHUNK - 1) / CHUNK;
    const int partBlocks = (E + PCHUNK - 1) / PCHUNK;
    const int tileBlocks = (N + 63) / 64;
    const int aggBlocks  = (N + 7) / 8;   // 2 dsts/wave * 4 waves

    k_pack<<<176, 64, 0, stream>>>(gatW, atS, atD, W1, W2, WgP, W1P, W2P);
    k_xcast<<<(N * D / 4 + 255) / 256, 256, 0, stream>>>(x, xb, N * D / 4);

    hipMemsetAsync(bcnt, 0, (size_t)4 * NB * 4, stream);
    k_bcount<<<dim3(cntBlocks, 4), 256, 0, stream>>>(e0, e1, e2, e3, bcnt, E, NB);
    k_bscan<<<dim3(1, 4), 1024, 0, stream>>>(bcnt, boff, bcur, prefix, E, N, NB);
    k_part<<<dim3(partBlocks, 4), 256, 0, stream>>>(e0, e1, e2, e3, bcur, staging, E, NB);
    k_place<<<dim3(NB, 4), 256, 0, stream>>>(staging, boff, prefix, srcs, N, E, NB);

    // layer 0
    k_gemm_h<<<tileBlocks, BLK, 0, stream>>>(xb, WgP, h, a_s, a_d, N);
    k_agg<<<dim3(aggBlocks, 4), BLK, 0, stream>>>(
        h, a_s, a_d, prefix, srcs, gatB, g, N, E);
    k_mlp<<<tileBlocks, BLK, 0, stream>>>(
        xb, g, W1P, b1, W2P, b2, xnext, N, 0,
        WgP + (size_t)40 * 512, h, a_s, a_d);   // fused layer-1 gemm_h

    // layer 1
    k_agg<<<dim3(aggBlocks, 4), BLK, 0, stream>>>(
        h, a_s, a_d, prefix, srcs, gatB + (size_t)4 * D, g, N, E);
    k_mlp<<<tileBlocks, BLK, 0, stream>>>(
        xnext, g, W1P + (size_t)40 * 512, b1 + D, W2P + (size_t)8 * 512, b2 + D,
        out, N, 1, nullptr, nullptr, nullptr, nullptr);
}